// Round 9
// baseline (88.432 us; speedup 1.0000x reference)
//
#include <hip/hip_runtime.h>
#include <hip/hip_bf16.h>

typedef __bf16 bf16x8 __attribute__((ext_vector_type(8)));
typedef float  f32x4  __attribute__((ext_vector_type(4)));

#define MFMA(a, b, c) __builtin_amdgcn_mfma_f32_16x16x32_bf16((a), (b), (c), 0, 0, 0)

// R9: R8 (barrier-free m-split, passed @77.7us) + EARLY register prefetch.
// Mechanism: in R1-R8 every wave had zero outstanding HBM loads during its
// compute phase (convoying; HBM duty ~75%). Register prefetch across a round
// only survives in a barrier-free loop (the compiler drains vmcnt at
// __syncthreads -> R2/R7's cross-barrier prefetches were dead on arrival).
// Here: loads for tile t+1 issue right after tile t's vr->fragment conversion
// (vr registers die there and are reused -> zero extra pressure), pinned by a
// single sched_barrier(0). Loads fly across MFMA+HF+F+softmax ~90% of round.
//  - w1 B-frags staged once in LDS (16KB, lane-linear, conflict-free).
//  - H in wave-private LDS slice (4KB/wave), same-wave in-order DS ops.
//  - Precision: x/w1/wp hi-only bf16, w2 split hi/lo (absmax pinned at 2^-8
//    across every precision variant R1-R8).
// LDS 32KB; VGPR est ~115 -> 3 blocks/CU at (256,3); zero loop barriers.

__device__ __forceinline__ int swz(int row, int byteInRow) {
    return row * 256 + (byteInRow ^ ((row & 7) << 4));
}

__global__ __launch_bounds__(256, 3) void edge_moe_kernel(
    const float* __restrict__ x,  const float* __restrict__ w1,
    const float* __restrict__ b1, const float* __restrict__ w2,
    const float* __restrict__ b2, const float* __restrict__ wp,
    float* __restrict__ outFused, float* __restrict__ outAlpha, int E)
{
    __shared__ __align__(16) char lds[32768];
    char* W1F = lds;               // [combo=kk*4+nt][lane] bf16x8 : 16KB
    char* HFB = lds + 16384;       // 4 waves x 4KB wave-private [16][64] f32, swz

    const int tid  = threadIdx.x;
    const int lane = tid & 63;
    const int wid  = tid >> 6;
    const int lc   = lane & 15;
    const int lg   = lane >> 4;
    char* HFW = HFB + wid * 4096;

    // ---- Stage w1 B-fragments to LDS (hi-only), wave w covers combos 4w..4w+3 ----
    // B-frag (16x16x32): lane holds B[k = kk*32 + lg*8 + j][n = nt*16 + lc].
#pragma unroll
    for (int i = 0; i < 4; ++i) {
        int combo = wid * 4 + i;
        int kk = combo >> 2, nt = combo & 3;
        bf16x8 h;
#pragma unroll
        for (int j = 0; j < 8; ++j) {
            int kidx = kk * 32 + lg * 8 + j;
            h[j] = (__bf16)w1[kidx * 64 + nt * 16 + lc];
        }
        *(bf16x8*)(W1F + combo * 1024 + lane * 16) = h;
    }

    // ---- w2 (split hi/lo) and wp (hi) B-fragments in registers ----
    bf16x8 w2h[2], w2l[2];
#pragma unroll
    for (int kk = 0; kk < 2; ++kk) {
        bf16x8 h, l;
#pragma unroll
        for (int j = 0; j < 8; ++j) {
            int kidx = kk * 32 + lg * 8 + j;
            float v = (lc < 8) ? w2[kidx * 8 + lc] : 0.0f;
            __bf16 hb = (__bf16)v;
            h[j] = hb; l[j] = (__bf16)(v - (float)hb);
        }
        w2h[kk] = h; w2l[kk] = l;
    }
    bf16x8 wph[4];
#pragma unroll
    for (int kk = 0; kk < 4; ++kk) {
        bf16x8 h;
#pragma unroll
        for (int j = 0; j < 8; ++j) {
            int kidx = kk * 32 + lg * 8 + j;
            h[j] = (lc < 8) ? (__bf16)wp[kidx * 8 + lc] : (__bf16)0.0f;
        }
        wph[kk] = h;
    }
    float b1v[4];
#pragma unroll
    for (int nt = 0; nt < 4; ++nt) b1v[nt] = b1[nt * 16 + lc];
    const float b2v = (lc < 8) ? b2[lc] : 0.0f;

    __syncthreads();   // the ONLY barrier: W1F staged and visible

    const int ntiles = (E + 63) >> 6;

    float4 vr[4][2];   // in-flight x row chunks; consumed+reissued each iter

#define LOADX(TT) do {                                                        \
        long long _e = (long long)(TT) * 64 + wid * 16 + lc;                  \
        if (_e > (long long)E - 1) _e = (long long)E - 1;                     \
        const float* _xr = x + (size_t)_e * 128;                              \
        _Pragma("unroll")                                                     \
        for (int _kk = 0; _kk < 4; ++_kk) {                                   \
            const float4* _p = (const float4*)(_xr + _kk * 32 + lg * 8);      \
            vr[_kk][0] = _p[0];                                               \
            vr[_kk][1] = _p[1];                                               \
        }                                                                     \
    } while (0)

    // Prologue: first tile's loads in flight.
    if (blockIdx.x < ntiles) LOADX(blockIdx.x);

    for (int tile = blockIdx.x; tile < ntiles; tile += gridDim.x) {
        const long long eb = (long long)tile * 64;

        // ---- Convert vr(t) -> A-fragments (vr dies here) ----
        bf16x8 axh[4];
#pragma unroll
        for (int kk = 0; kk < 4; ++kk) {
            f32x4 x0, x1;
#pragma unroll
            for (int j = 0; j < 4; ++j) { x0[j] = vr[kk][0][j == 0 ? 0 : j]; }
            x0[0] = vr[kk][0].x; x0[1] = vr[kk][0].y; x0[2] = vr[kk][0].z; x0[3] = vr[kk][0].w;
            x1[0] = vr[kk][1].x; x1[1] = vr[kk][1].y; x1[2] = vr[kk][1].z; x1[3] = vr[kk][1].w;
            bf16x8 a;
#pragma unroll
            for (int j = 0; j < 4; ++j) {
                a[j]     = (__bf16)x0[j];
                a[j + 4] = (__bf16)x1[j];
            }
            axh[kk] = a;
        }

        // ---- EARLY prefetch: issue x(t+1) loads now; in flight across all
        //      compute below (no barriers anywhere to drain vmcnt). ----
        {
            int nxt = tile + (int)gridDim.x;
            if (nxt < ntiles) LOADX(nxt);
        }
        __builtin_amdgcn_sched_barrier(0);   // pin issue point: loads can't sink

        // ---- H = relu(x @ w1 + b1): 16 MFMA, B-frags from LDS (conflict-free) ----
        f32x4 acc[4] = {{0.f,0.f,0.f,0.f},{0.f,0.f,0.f,0.f},{0.f,0.f,0.f,0.f},{0.f,0.f,0.f,0.f}};
#pragma unroll
        for (int kk = 0; kk < 4; ++kk)
#pragma unroll
            for (int nt = 0; nt < 4; ++nt) {
                bf16x8 wf = *(const bf16x8*)(W1F + (kk * 4 + nt) * 1024 + lane * 16);
                acc[nt] = MFMA(axh[kk], wf, acc[nt]);
            }

        // ---- relu+bias -> wave-private HF (C-layout row = lg*4+r, col = nt*16+lc) ----
#pragma unroll
        for (int nt = 0; nt < 4; ++nt)
#pragma unroll
            for (int r = 0; r < 4; ++r) {
                float hv = fmaxf(acc[nt][r] + b1v[nt], 0.f);
                *(float*)(HFW + swz(lg * 4 + r, (nt * 16 + lc) * 4)) = hv;
            }
        asm volatile("" ::: "memory");   // same-wave DS ordering (HW in-order)

        // ---- logits = H@w2 + b2 (H->bf16 once, w2 split); scores = x@wp (axh) ----
        f32x4 lac = {0.f, 0.f, 0.f, 0.f};
        f32x4 sac = {0.f, 0.f, 0.f, 0.f};
#pragma unroll
        for (int kk = 0; kk < 2; ++kk) {
            int base = kk * 128 + lg * 32;     // f32 bytes: k = kk*32 + lg*8
            f32x4 h0 = *(const f32x4*)(HFW + swz(lc, base));
            f32x4 h1 = *(const f32x4*)(HFW + swz(lc, base + 16));
            bf16x8 hh;
#pragma unroll
            for (int j = 0; j < 4; ++j) {
                hh[j]     = (__bf16)h0[j];
                hh[j + 4] = (__bf16)h1[j];
            }
            lac = MFMA(hh, w2h[kk], lac);
            lac = MFMA(hh, w2l[kk], lac);
        }
#pragma unroll
        for (int kk = 0; kk < 4; ++kk) {
            sac = MFMA(axh[kk], wph[kk], sac);
        }
        asm volatile("" ::: "memory");   // this iter's HF reads before next writes

        // ---- Softmax over 8 cols (lanes lc<8; no max-sub) + fused dot ----
#pragma unroll
        for (int r = 0; r < 4; ++r) {
            float lv = lac[r] + b2v;           // TEMPERATURE = 1.0
            float p = __expf(lv);
            float s  = p;
            float fs = p * sac[r];
            s  += __shfl_xor(s, 1);  fs += __shfl_xor(fs, 1);
            s  += __shfl_xor(s, 2);  fs += __shfl_xor(fs, 2);
            s  += __shfl_xor(s, 4);  fs += __shfl_xor(fs, 4);
            float inv = 1.0f / s;
            float alpha = p * inv;
            float fv = fs * inv;
            long long edge = eb + wid * 16 + lg * 4 + r;
            if (edge < E) {
                if (lc < 8) outAlpha[edge * 8 + lc] = alpha;
                if (lc == 0) outFused[edge] = fv;
            }
        }
        // no barrier: next iteration is fully wave-local
    }
#undef LOADX
}

extern "C" void kernel_launch(void* const* d_in, const int* in_sizes, int n_in,
                              void* d_out, int out_size, void* d_ws, size_t ws_size,
                              hipStream_t stream) {
    const float* x  = (const float*)d_in[0];
    const float* w1 = (const float*)d_in[1];
    const float* b1 = (const float*)d_in[2];
    const float* w2 = (const float*)d_in[3];
    const float* b2 = (const float*)d_in[4];
    const float* wp = (const float*)d_in[5];

    const int E = in_sizes[0] / 128;
    float* outF = (float*)d_out;
    float* outA = outF + E;

    const int ntiles = (E + 63) >> 6;
    const int blocks = ntiles < 1024 ? ntiles : 1024;
    edge_moe_kernel<<<blocks, 256, 0, stream>>>(x, w1, b1, w2, b2, wp, outF, outA, E);
}

// Round 10
// 73.351 us; speedup vs baseline: 1.2056x; 1.2056x over previous
//
#include <hip/hip_runtime.h>
#include <hip/hip_bf16.h>

typedef __bf16 bf16x8 __attribute__((ext_vector_type(8)));
typedef float  f32x4  __attribute__((ext_vector_type(4)));

#define MFMA(a, b, c) __builtin_amdgcn_mfma_f32_16x16x32_bf16((a), (b), (c), 0, 0, 0)

// R10 = R4 verbatim (measured best: 73.5us, absmax 0.0039).
// R4's n-split skeleton:
//  - x stored bf16-only in LDS (16KB); the hi/lo split moved to the WEIGHT side
//    (w1h+w1l, w2h+w2l, wph+wpl in registers, built once).
//  - phase D peels mt==wid first and stashes axh[kk] -> phase F scores MFMAs
//    reuse them; no x re-read.
//  - H goes through LDS f32 (cross-wave), converted once to bf16 (no hl),
//    2 MFMAs vs w2h/w2l.
//  - softmax: no max-subtract (|logits| bounded), fused sum+dot, 6 shuffles/r.
// LDS 32KB (XH 16K + HF 16K) -> 3 blocks/CU.
//
// Post-R9 note: six independent levers (register prefetch x2, occupancy-4,
// 2-barrier, barrier-free, gload_lds) all landed at 74-88us vs this kernel's
// 73.5 -> the 74us plateau is the practical BW ceiling for this access mix
// (~4.8 TB/s on mixed 327MB coalesced read + 20.5MB scattered write + compute).

__device__ __forceinline__ int swz(int row, int byteInRow) {
    return row * 256 + (byteInRow ^ ((row & 7) << 4));
}

__global__ __launch_bounds__(256, 3) void edge_moe_kernel(
    const float* __restrict__ x,  const float* __restrict__ w1,
    const float* __restrict__ b1, const float* __restrict__ w2,
    const float* __restrict__ b2, const float* __restrict__ wp,
    float* __restrict__ outFused, float* __restrict__ outAlpha, int E)
{
    __shared__ __align__(16) char lds[32768];
    char* XH = lds;
    char* HF = lds + 16384;

    const int tid  = threadIdx.x;
    const int lane = tid & 63;
    const int wid  = tid >> 6;   // wave id 0..3 = H-col tile owner (n-split)
    const int lc   = lane & 15;
    const int lg   = lane >> 4;

    // ---- Weight B-fragments, split hi/lo on the WEIGHT side ----
    // B-frag (16x16x32): lane holds B[k = kk*32 + lg*8 + j][n], j=0..7.
    bf16x8 w1h[4], w1l[4];       // n = wid*16+lc (this wave's n-tile)
#pragma unroll
    for (int kk = 0; kk < 4; ++kk) {
        bf16x8 h, l;
#pragma unroll
        for (int j = 0; j < 8; ++j) {
            int kidx = kk * 32 + lg * 8 + j;
            float v = w1[kidx * 64 + wid * 16 + lc];
            __bf16 hb = (__bf16)v;
            h[j] = hb; l[j] = (__bf16)(v - (float)hb);
        }
        w1h[kk] = h; w1l[kk] = l;
    }
    bf16x8 w2h[2], w2l[2];       // n = lc (<8), padded 0
#pragma unroll
    for (int kk = 0; kk < 2; ++kk) {
        bf16x8 h, l;
#pragma unroll
        for (int j = 0; j < 8; ++j) {
            int kidx = kk * 32 + lg * 8 + j;
            float v = (lc < 8) ? w2[kidx * 8 + lc] : 0.0f;
            __bf16 hb = (__bf16)v;
            h[j] = hb; l[j] = (__bf16)(v - (float)hb);
        }
        w2h[kk] = h; w2l[kk] = l;
    }
    bf16x8 wph[4], wpl[4];       // n = lc (<8), padded 0
#pragma unroll
    for (int kk = 0; kk < 4; ++kk) {
        bf16x8 h, l;
#pragma unroll
        for (int j = 0; j < 8; ++j) {
            int kidx = kk * 32 + lg * 8 + j;
            float v = (lc < 8) ? wp[kidx * 8 + lc] : 0.0f;
            __bf16 hb = (__bf16)v;
            h[j] = hb; l[j] = (__bf16)(v - (float)hb);
        }
        wph[kk] = h; wpl[kk] = l;
    }
    const float b1v = b1[wid * 16 + lc];          // col fixed per wave (n-split)
    const float b2v = (lc < 8) ? b2[lc] : 0.0f;

    const int ntiles = (E + 63) >> 6;
    const int r0 = tid >> 4;          // 0..15 (x-load row)
    const int c8 = tid & 15;          // 8-float column chunk
    const int arow = wid * 16 + lc;   // this wave's phase-F A-frag row

    for (int tile = blockIdx.x; tile < ntiles; tile += gridDim.x) {
        const long long eb = (long long)tile * 64;

        // ---- Load x tile [64][128] f32, coalesced ----
        float4 vr[4][2];
#pragma unroll
        for (int it = 0; it < 4; ++it) {
            long long e = eb + r0 + it * 16;
            if (e > (long long)E - 1) e = E - 1;
            const float4* p = (const float4*)(x + (size_t)e * 128 + c8 * 8);
            vr[it][0] = p[0];
            vr[it][1] = p[1];
        }
        __syncthreads();   // barrier 1: XH(t-1)/HF(t-1) readers done

        // ---- A: convert to bf16 (hi only), write LDS (swizzled) ----
#pragma unroll
        for (int it = 0; it < 4; ++it) {
            int row = r0 + it * 16;
            bf16x8 h;
            const float* f = (const float*)&vr[it][0];
#pragma unroll
            for (int j = 0; j < 8; ++j) h[j] = (__bf16)f[j];
            *(bf16x8*)(XH + swz(row, c8 * 16)) = h;
        }
        __syncthreads();   // barrier 2: x(t) ready

        // ---- D: H = relu(x@w1+b1) for n-tile wid, all 4 m-tiles ----
        // Peel mtt=0 (mt = wid) and stash its A-frags for phase F's x@wp.
        bf16x8 axh[4];
        f32x4 acc[4] = {{0.f,0.f,0.f,0.f},{0.f,0.f,0.f,0.f},{0.f,0.f,0.f,0.f},{0.f,0.f,0.f,0.f}};
#pragma unroll
        for (int kk = 0; kk < 4; ++kk) {
            axh[kk] = *(const bf16x8*)(XH + swz(arow, kk * 64 + lg * 16));
            acc[0] = MFMA(axh[kk], w1h[kk], acc[0]);
            acc[0] = MFMA(axh[kk], w1l[kk], acc[0]);
        }
#pragma unroll
        for (int mtt = 1; mtt < 4; ++mtt) {
            const int mt = (wid + mtt) & 3;
            const int row = mt * 16 + lc;
#pragma unroll
            for (int kk = 0; kk < 4; ++kk) {
                bf16x8 ah = *(const bf16x8*)(XH + swz(row, kk * 64 + lg * 16));
                acc[mtt] = MFMA(ah, w1h[kk], acc[mtt]);
                acc[mtt] = MFMA(ah, w1l[kk], acc[mtt]);
            }
        }
        // bias + relu -> HF f32 (C-layout: row = mt*16+lg*4+r, col = wid*16+lc)
#pragma unroll
        for (int mtt = 0; mtt < 4; ++mtt) {
            const int mt = (wid + mtt) & 3;
#pragma unroll
            for (int r = 0; r < 4; ++r) {
                float hv = fmaxf(acc[mtt][r] + b1v, 0.f);
                *(float*)(HF + swz(mt * 16 + lg * 4 + r, (wid * 16 + lc) * 4)) = hv;
            }
        }
        __syncthreads();   // barrier 3: H ready (cross-wave)

        // ---- F: logits = H@w2 + b2 (H->bf16 once, w2 split); scores from axh ----
        f32x4 lac = {0.f, 0.f, 0.f, 0.f};
        f32x4 sac = {0.f, 0.f, 0.f, 0.f};
#pragma unroll
        for (int kk = 0; kk < 2; ++kk) {
            int base = kk * 128 + lg * 32;     // f32 bytes: k = kk*32 + lg*8
            f32x4 h0 = *(const f32x4*)(HF + swz(arow, base));
            f32x4 h1 = *(const f32x4*)(HF + swz(arow, base + 16));
            bf16x8 hh;
#pragma unroll
            for (int j = 0; j < 4; ++j) {
                hh[j]     = (__bf16)h0[j];
                hh[j + 4] = (__bf16)h1[j];
            }
            lac = MFMA(hh, w2h[kk], lac);
            lac = MFMA(hh, w2l[kk], lac);
        }
#pragma unroll
        for (int kk = 0; kk < 4; ++kk) {
            sac = MFMA(axh[kk], wph[kk], sac);
            sac = MFMA(axh[kk], wpl[kk], sac);
        }

        // ---- Softmax over 8 cols (lanes lc<8; no max-sub) + fused dot ----
#pragma unroll
        for (int r = 0; r < 4; ++r) {
            float lv = lac[r] + b2v;           // TEMPERATURE = 1.0
            float p = __expf(lv);
            float s  = p;
            float fs = p * sac[r];
            s  += __shfl_xor(s, 1);  fs += __shfl_xor(fs, 1);
            s  += __shfl_xor(s, 2);  fs += __shfl_xor(fs, 2);
            s  += __shfl_xor(s, 4);  fs += __shfl_xor(fs, 4);
            float inv = 1.0f / s;
            float alpha = p * inv;
            float fv = fs * inv;
            long long edge = eb + wid * 16 + lg * 4 + r;
            if (edge < E) {
                if (lc < 8) outAlpha[edge * 8 + lc] = alpha;
                if (lc == 0) outFused[edge] = fv;
            }
        }
        // loop-top barrier orders next tile's XH/HF overwrite
    }
}

extern "C" void kernel_launch(void* const* d_in, const int* in_sizes, int n_in,
                              void* d_out, int out_size, void* d_ws, size_t ws_size,
                              hipStream_t stream) {
    const float* x  = (const float*)d_in[0];
    const float* w1 = (const float*)d_in[1];
    const float* b1 = (const float*)d_in[2];
    const float* w2 = (const float*)d_in[3];
    const float* b2 = (const float*)d_in[4];
    const float* wp = (const float*)d_in[5];

    const int E = in_sizes[0] / 128;
    float* outF = (float*)d_out;
    float* outA = outF + E;

    const int ntiles = (E + 63) >> 6;
    const int blocks = ntiles < 768 ? ntiles : 768;
    edge_moe_kernel<<<blocks, 256, 0, stream>>>(x, w1, b1, w2, b2, wp, outF, outA, E);
}